// Round 23
// baseline (39.075 us; speedup 1.0000x reference)
//
#include <hip/hip_runtime.h>
#include <math.h>

// FusedAttentionWithRPB round 23: r18 base (barrier-free, 38.5us reproduced)
// + QA staging: prep also builds Q-AUGMENTED fragment-major tiles (Q*scale |
// onehot(qx) | onehot(qy)) so main's prologue is 4 coalesced 16B loads
// instead of 4 scattered Q loads + px/py loads + pack/onehot VALU, and the
// work is done once per (bh,qi) instead of np times. All else r18-verbatim.

constexpr int Bc = 4, Hc = 8, Sc = 1024, Dc = 64;
constexpr int NT = 256;
constexpr float LOG2E = 1.44269504f;

constexpr size_t KA_BYTES   = (size_t)32 * 16 * 16384;            // 8 MB
constexpr size_t QA_BYTES   = (size_t)32 * 16 * 16384;            // 8 MB
constexpr size_t VT_BYTES   = (size_t)32 * 16 * 8192;             // 4 MB
constexpr size_t PART_OFF   = KA_BYTES + QA_BYTES + VT_BYTES;
constexpr size_t PART_BYTES = (size_t)32 * 12 * 3 * 64 * 66 * sizeof(float);
constexpr size_t WS_SPLIT   = PART_OFF + PART_BYTES;

typedef __attribute__((ext_vector_type(8))) short bf16x8;
typedef __attribute__((ext_vector_type(4))) float f32x4;

// chunk tables: cid -> (qi, ktb, kte, part), heavy-first (LPT)  [validated]
__device__ __constant__ signed char CQI[32] =
  {15,11,11,10,15,15,14,14,14,13,13,12,10, 9, 9, 8,13,12,12, 8, 7, 7, 6, 3, 6, 5, 5, 4, 2, 4, 1, 0};
__device__ __constant__ signed char CKTB[32] =
  {10, 0, 6, 5, 0, 5, 0, 5,10, 4, 9, 8, 0, 0, 5, 4, 0, 0, 4, 0, 0, 4, 3, 0, 0, 0, 3, 2, 0, 0, 0, 0};
__device__ __constant__ signed char CKTE[32] =
  {16, 6,12,11, 5,10, 5,10,15, 9,14,13, 5, 5,10, 9, 4, 4, 8, 4, 4, 8, 7, 4, 3, 3, 6, 5, 3, 2, 2, 1};
__device__ __constant__ signed char CPT[32] =
  { 2, 0, 1, 1, 0, 1, 0, 1, 2, 1, 2, 2, 0, 0, 1, 1, 0, 0, 1, 0, 0, 1, 1, 0, 0, 0, 1, 1, 0, 0, 0, 0};

__device__ __forceinline__ unsigned short f2bf(float f) {
  union { float f; unsigned u; } x; x.f = f;
  unsigned r = x.u + 0x7FFFu + ((x.u >> 16) & 1u);
  return (unsigned short)(r >> 16);
}
__device__ __forceinline__ bf16x8 pack8(float4 a, float4 b) {
  bf16x8 r;
  r[0] = (short)f2bf(a.x); r[1] = (short)f2bf(a.y);
  r[2] = (short)f2bf(a.z); r[3] = (short)f2bf(a.w);
  r[4] = (short)f2bf(b.x); r[5] = (short)f2bf(b.y);
  r[6] = (short)f2bf(b.z); r[7] = (short)f2bf(b.w);
  return r;
}
__device__ __forceinline__ float4 sc4(float4 a, float s) {
  return make_float4(a.x*s, a.y*s, a.z*s, a.w*s);
}
__device__ __forceinline__ float ex2(float x) {
  return __builtin_amdgcn_exp2f(x);
}
// swizzled byte offset inside a 64x64 bf16 tile (128B rows) for Ps
__device__ __forceinline__ int swzb(int row, int col) {
  return ((row << 7) + (col << 1)) ^ ((row & 7) << 4);
}
template<int C>
__device__ __forceinline__ float dppf(float x) {
  return __int_as_float(__builtin_amdgcn_update_dpp(
      __float_as_int(x), __float_as_int(x), C, 0xF, 0xF, false));
}
__device__ __forceinline__ float red_max16(float x) {
  x = fmaxf(x, dppf<0xB1>(x));  x = fmaxf(x, dppf<0x4E>(x));
  x = fmaxf(x, dppf<0x141>(x)); x = fmaxf(x, dppf<0x140>(x));
  return x;
}
__device__ __forceinline__ float red_sum16(float x) {
  x += dppf<0xB1>(x);  x += dppf<0x4E>(x);
  x += dppf<0x141>(x); x += dppf<0x140>(x);
  return x;
}

// ---- fused pre-pass.
// Blocks 0-511 (bh,kt):   KA tiles (r18, validated): 16 frags x 1KB; frag f
//   (ct=f>>2, ks=f&3), lane l=16lg+lr holds KA[key=16ct+lr][slot=4ks+lg];
//   slots 0-7 K dims, 8-11 x-bias cols, 12-15 y-bias cols (bias * log2e).
// Blocks 512-1023 (bh,u): QA tiles (NEW, same geometry): frag f (w=f>>2,
//   ks=f&3), lane l holds QA[row=16w+lr][slot=4ks+lg]; slots 0-7 = Q dims
//   * 0.125*log2e, 8-11 = onehot(qx) cols, 12-15 = onehot(qy) cols.
// Blocks 1024-1535 (bh,tt): Vt fragment-major (r14, validated).
__global__ __launch_bounds__(256) void prep(
    const float* __restrict__ kg, const float* __restrict__ qg,
    const float* __restrict__ vg,
    const int* __restrict__ px, const int* __restrict__ py,
    const float* __restrict__ bx, const float* __restrict__ by,
    unsigned short* __restrict__ wsKA, unsigned short* __restrict__ wsQA,
    unsigned short* __restrict__ wsVt)
{
  __shared__ float tile[64 * 68];
  __shared__ float bxh[61], byh[61];
  __shared__ int kxs[64], kys[64];
  const int t = threadIdx.x;
  if (blockIdx.x < 512) {
    const int bh = blockIdx.x >> 4, kt = blockIdx.x & 15;
    const int b = bh >> 3, h = bh & 7;
    const int row = t >> 2, c4 = t & 3;
    const float4* src = (const float4*)(kg + ((size_t)bh * Sc + kt*64 + row) * Dc + c4*16);
    #pragma unroll
    for (int jj = 0; jj < 4; ++jj)
      *(float4*)&tile[row * 68 + c4*16 + 4*jj] = src[jj];
    if (t < 61)                   bxh[t]      = bx[t * Hc + h] * LOG2E;
    else if (t >= 64 && t < 125)  byh[t - 64] = by[(t - 64) * Hc + h] * LOG2E;
    if (t < 64) { kxs[t] = px[b*Sc + kt*64 + t]; kys[t] = py[b*Sc + kt*64 + t]; }
    __syncthreads();
    const int l = t & 63, fg = t >> 6;
    const int lg = l >> 4, lr = l & 15;
    unsigned short* tbase = wsKA + (size_t)(bh * 16 + kt) * 8192;
    #pragma unroll
    for (int ff = 0; ff < 4; ++ff) {
      const int f = ff * 4 + fg;
      const int ct = f >> 2, ks = f & 3;
      const int keyl = 16*ct + lr, slot = 4*ks + lg;
      bf16x8 out;
      if (slot < 8) {
        float4 a = *(const float4*)&tile[keyl * 68 + slot*8];
        float4 bb = *(const float4*)&tile[keyl * 68 + slot*8 + 4];
        out = pack8(a, bb);
      } else if (slot < 12) {
        const int p = slot - 8, kx = kxs[keyl];
        #pragma unroll
        for (int j = 0; j < 8; ++j) {
          int ix = 8*p + j - kx; ix = ix < -30 ? -30 : (ix > 30 ? 30 : ix);
          out[j] = (short)f2bf(bxh[ix + 30]);
        }
      } else {
        const int p = slot - 12, ky = kys[keyl];
        #pragma unroll
        for (int j = 0; j < 8; ++j) {
          int iy = 8*p + j - ky; iy = iy < -30 ? -30 : (iy > 30 ? 30 : iy);
          out[j] = (short)f2bf(byh[iy + 30]);
        }
      }
      *(bf16x8*)(tbase + f * 512 + l * 8) = out;
    }
  } else if (blockIdx.x < 1024) {
    const int bid = blockIdx.x - 512;
    const int bh = bid >> 4, u = bid & 15;
    const int b = bh >> 3;
    const int row = t >> 2, c4 = t & 3;
    const float4* src = (const float4*)(qg + ((size_t)bh * Sc + u*64 + row) * Dc + c4*16);
    #pragma unroll
    for (int jj = 0; jj < 4; ++jj)
      *(float4*)&tile[row * 68 + c4*16 + 4*jj] = src[jj];
    if (t < 64) { kxs[t] = px[b*Sc + u*64 + t]; kys[t] = py[b*Sc + u*64 + t]; }
    __syncthreads();
    const int l = t & 63, fg = t >> 6;
    const int lg = l >> 4, lr = l & 15;
    const float qs = 0.125f * LOG2E;
    const unsigned short one = f2bf(1.0f);
    unsigned short* tbase = wsQA + (size_t)(bh * 16 + u) * 8192;
    #pragma unroll
    for (int ff = 0; ff < 4; ++ff) {
      const int f = ff * 4 + fg;
      const int w_ = f >> 2, ks = f & 3;
      const int rowl = 16*w_ + lr, slot = 4*ks + lg;
      bf16x8 out;
      if (slot < 8) {
        float4 a = sc4(*(const float4*)&tile[rowl * 68 + slot*8], qs);
        float4 bb = sc4(*(const float4*)&tile[rowl * 68 + slot*8 + 4], qs);
        out = pack8(a, bb);
      } else if (slot < 12) {
        const int p = slot - 8, qx = kxs[rowl];
        #pragma unroll
        for (int j = 0; j < 8; ++j)
          out[j] = (qx == 8*p + j) ? (short)one : (short)0;
      } else {
        const int p = slot - 12, qy = kys[rowl];
        #pragma unroll
        for (int j = 0; j < 8; ++j)
          out[j] = (qy == 8*p + j) ? (short)one : (short)0;
      }
      *(bf16x8*)(tbase + f * 512 + l * 8) = out;
    }
  } else {
    const int bid = blockIdx.x - 1024;
    const int bh = bid >> 4, tt = bid & 15;
    const int row = t >> 2, c4 = t & 3;
    const float4* src = (const float4*)(vg + ((size_t)bh * Sc + tt*64 + row) * Dc + c4*16);
    #pragma unroll
    for (int jj = 0; jj < 4; ++jj)
      *(float4*)&tile[row * 68 + c4*16 + 4*jj] = src[jj];
    __syncthreads();
    const int d = t & 63, cg = t >> 6;
    const int nt_ = d >> 4, lr = d & 15;
    unsigned short* tbase = wsVt + (size_t)(bh * 16 + tt) * 4096;
    #pragma unroll
    for (int cc = 0; cc < 2; ++cc) {
      const int c = 2*cg + cc;            // keys [8c, 8c+8)
      const int ks = c >> 2, lg = c & 3;
      bf16x8 vv;
      #pragma unroll
      for (int jj = 0; jj < 8; ++jj)
        vv[jj] = (short)f2bf(tile[(8*c + jj) * 68 + d]);
      *(bf16x8*)(tbase + (nt_*2 + ks) * 512 + (16*lg + lr) * 8) = vv;
    }
  }
}

// ---- main kernel: barrier-free; aq from QA tile (4 coalesced loads)
__global__ __launch_bounds__(NT, 3) void attn_rpb_mfma22(
    const int* __restrict__ pz, const float* __restrict__ bz,
    const unsigned short* __restrict__ wsKA, const unsigned short* __restrict__ wsQA,
    const unsigned short* __restrict__ wsVt,
    float* __restrict__ outg, float* __restrict__ wsPart, int mode)
{
  int qi, ktb, kte, part, np, bh;
  {
    const int j = blockIdx.x;
    if (mode == 0) {
      const int idx = j & 255; bh = idx >> 3; const int r3 = idx & 7;
      qi = (j < 256) ? (15 - r3) : r3;
      ktb = 0; kte = qi + 1; part = 0; np = 1;
    } else {
      bh = j & 31;
      const int cid = j >> 5;
      qi = CQI[cid]; ktb = CKTB[cid]; kte = CKTE[cid]; part = CPT[cid];
      np = (qi < 4) ? 1 : ((qi < 12) ? 2 : 3);
    }
  }
  const int h = bh & 7, b = bh >> 3;

  __shared__ unsigned short Ps[64 * 64];   // 8 KB, wave-private rows
  __shared__ float BZ2[256];

  const int t  = threadIdx.x;
  const int w  = t >> 6;
  const int l  = t & 63;
  const int lg = l >> 4;
  const int lr = l & 15;
  const size_t bhOff = (size_t)bh * Sc;
  const int q0 = qi * 64;

  const char* kaSrc = (const char*)wsKA;
  const char* vtSrc = (const char*)wsVt;

  // ---- prologue: BZ2; aq from QA tile (coalesced fragment loads)
  {
    int dzz = (t >> 4) - (t & 15); dzz = dzz < -10 ? -10 : (dzz > 10 ? 10 : dzz);
    BZ2[t] = bz[(dzz + 10) * Hc + h] * LOG2E;
  }
  bf16x8 aq[4];
  {
    const char* qaTile = (const char*)wsQA + (size_t)(bh*16 + qi) * 16384 + l*16;
    #pragma unroll
    for (int ks = 0; ks < 4; ++ks)
      aq[ks] = *(const bf16x8*)(qaTile + (w*4 + ks) * 1024);
  }
  int rowg[4], qz16[4];
  #pragma unroll
  for (int r = 0; r < 4; ++r) {
    const int rl = 16*w + 4*lg + r;
    rowg[r] = q0 + rl;
    qz16[r] = pz[b*Sc + q0 + rl] << 4;
  }

  float mrow[4], lsumP[4];
  f32x4 O[4];
  const f32x4 zero4 = {0.f, 0.f, 0.f, 0.f};
  #pragma unroll
  for (int r = 0; r < 4; ++r) { mrow[r] = -INFINITY; lsumP[r] = 0.f; }
  #pragma unroll
  for (int nt_ = 0; nt_ < 4; ++nt_) O[nt_] = zero4;

  __syncthreads();   // BZ2 visible (ONLY barrier in the kernel)

  for (int kt = ktb; kt < kte; ++kt) {
    const int k0 = kt * 64;
    const char* kaTile = kaSrc + (size_t)(bh*16 + kt) * 16384 + l*16;
    const char* vtile  = vtSrc + (size_t)(bh*16 + kt) * 8192 + l*16;

    // ---- V frags + kz -> regs (coalesced, L1/L2-hot)
    bf16x8 vv[8];
    #pragma unroll
    for (int f = 0; f < 8; ++f)
      vv[f] = *(const bf16x8*)(vtile + f*1024);
    int kzv[4];
    #pragma unroll
    for (int ct = 0; ct < 4; ++ct) kzv[ct] = pz[b*Sc + k0 + 16*ct + lr];

    // ---- S = [Q|onehot] x KA^T  (K=128, 16 MFMA; frags coalesced)
    f32x4 s[4];
    #pragma unroll
    for (int ct = 0; ct < 4; ++ct) {
      s[ct] = zero4;
      #pragma unroll
      for (int ks = 0; ks < 4; ++ks) {
        bf16x8 bk = *(const bf16x8*)(kaTile + (ct*4 + ks) * 1024);
        s[ct] = __builtin_amdgcn_mfma_f32_16x16x32_bf16(aq[ks], bk, s[ct], 0, 0, 0);
      }
    }

    // ---- z-bias + causal mask
    const bool diag = (kt == qi);
    #pragma unroll
    for (int ct = 0; ct < 4; ++ct) {
      const int colg = k0 + 16*ct + lr;
      #pragma unroll
      for (int r = 0; r < 4; ++r) {
        float val = s[ct][r] + BZ2[qz16[r] | kzv[ct]];
        if (diag && colg > rowg[r]) val = -INFINITY;
        s[ct][r] = val;
      }
    }

    // ---- online softmax: defer-max (log2 domain) + lazy lsum
    float tmax[4];
    #pragma unroll
    for (int r = 0; r < 4; ++r) {
      tmax[r] = fmaxf(fmaxf(s[0][r], s[1][r]), fmaxf(s[2][r], s[3][r]));
      tmax[r] = red_max16(tmax[r]);
    }
    float dmax = fmaxf(fmaxf(tmax[0] - mrow[0], tmax[1] - mrow[1]),
                       fmaxf(tmax[2] - mrow[2], tmax[3] - mrow[3]));
    if (__any(dmax > 11.5f)) {
      #pragma unroll
      for (int r = 0; r < 4; ++r) {
        const float mn = fmaxf(mrow[r], tmax[r]);
        const float alpha = ex2(mrow[r] - mn);
        mrow[r] = mn;
        lsumP[r] *= alpha;
        #pragma unroll
        for (int nt_ = 0; nt_ < 4; ++nt_) O[nt_][r] *= alpha;
      }
    }
    #pragma unroll
    for (int ct = 0; ct < 4; ++ct) {
      #pragma unroll
      for (int r = 0; r < 4; ++r)
        s[ct][r] = ex2(s[ct][r] - mrow[r]);
    }
    #pragma unroll
    for (int r = 0; r < 4; ++r)
      lsumP[r] += (s[0][r] + s[1][r]) + (s[2][r] + s[3][r]);

    // ---- P -> bf16 -> Ps (wave-private rows; in-wave ordering suffices)
    #pragma unroll
    for (int ct = 0; ct < 4; ++ct) {
      #pragma unroll
      for (int r = 0; r < 4; ++r)
        *(unsigned short*)((char*)Ps + swzb(16*w + 4*lg + r, 16*ct + lr)) = f2bf(s[ct][r]);
    }
    bf16x8 pa[2];
    pa[0] = *(const bf16x8*)((const char*)Ps + swzb(16*w + lr, 8*lg));
    pa[1] = *(const bf16x8*)((const char*)Ps + swzb(16*w + lr, 8*lg + 32));

    // ---- O += P V
    #pragma unroll
    for (int nt_ = 0; nt_ < 4; ++nt_) {
      #pragma unroll
      for (int ks = 0; ks < 2; ++ks)
        O[nt_] = __builtin_amdgcn_mfma_f32_16x16x32_bf16(pa[ks], vv[nt_*2 + ks], O[nt_], 0, 0, 0);
    }
    // no barrier: next iteration's loads are independent (pure reads)
  }

  // ---- epilogue: reduce lsum across the 16 lanes once
  float lsum[4];
  #pragma unroll
  for (int r = 0; r < 4; ++r) lsum[r] = red_sum16(lsumP[r]);

  if (np == 1) {
    #pragma unroll
    for (int r = 0; r < 4; ++r) {
      const float inv = 1.0f / lsum[r];
      #pragma unroll
      for (int nt_ = 0; nt_ < 4; ++nt_)
        outg[(bhOff + q0 + 16*w + 4*lg + r) * Dc + 16*nt_ + lr] = O[nt_][r] * inv;
    }
  } else {
    float* base = wsPart + ((((size_t)bh * 12 + (qi - 4)) * 3 + part) * 64) * 66;
    #pragma unroll
    for (int r = 0; r < 4; ++r) {
      float* rowp = base + (16*w + 4*lg + r) * 66;
      #pragma unroll
      for (int nt_ = 0; nt_ < 4; ++nt_)
        rowp[16*nt_ + lr] = O[nt_][r];
      if (lr == 0) { rowp[64] = mrow[r]; rowp[65] = lsum[r]; }
    }
  }
}

// merge 2-3 partials per (bh, qi>=4) row; m in LOG2 domain -> exp2 weights
__global__ __launch_bounds__(256) void attn_rpb_combine(
    const float* __restrict__ wsPart, float* __restrict__ outg)
{
  const int t = threadIdx.x;
  const int ridx = blockIdx.x * 4 + (t >> 6);
  const int d = t & 63;
  const int bh = ridx / 768;
  const int rem = ridx - bh * 768;
  const int qj = rem >> 6;
  const int rl = rem & 63;
  const float* p0 = wsPart + (((size_t)bh * 12 + qj) * 3 + 0) * 64 * 66 + (size_t)rl * 66;
  const float* p1 = p0 + 64 * 66;
  const float m0 = p0[64], l0 = p0[65];
  const float m1 = p1[64], l1 = p1[65];
  float m = fmaxf(m0, m1);
  float o, lc;
  if (qj >= 8) {
    const float* p2 = p1 + 64 * 66;
    const float m2 = p2[64], l2 = p2[65];
    m = fmaxf(m, m2);
    const float w0 = __builtin_amdgcn_exp2f(m0 - m);
    const float w1 = __builtin_amdgcn_exp2f(m1 - m);
    const float w2 = __builtin_amdgcn_exp2f(m2 - m);
    lc = l0 * w0 + l1 * w1 + l2 * w2;
    o  = p0[d] * w0 + p1[d] * w1 + p2[d] * w2;
  } else {
    const float w0 = __builtin_amdgcn_exp2f(m0 - m);
    const float w1 = __builtin_amdgcn_exp2f(m1 - m);
    lc = l0 * w0 + l1 * w1;
    o  = p0[d] * w0 + p1[d] * w1;
  }
  outg[((size_t)bh * Sc + (qj + 4) * 64 + rl) * Dc + d] = o / lc;
}

extern "C" void kernel_launch(void* const* d_in, const int* in_sizes, int n_in,
                              void* d_out, int out_size, void* d_ws, size_t ws_size,
                              hipStream_t stream) {
  const float* q  = (const float*)d_in[0];
  const float* k  = (const float*)d_in[1];
  const float* v  = (const float*)d_in[2];
  const int*   px = (const int*)d_in[3];
  const int*   py = (const int*)d_in[4];
  const int*   pz = (const int*)d_in[5];
  const float* bx = (const float*)d_in[6];
  const float* by = (const float*)d_in[7];
  const float* bz = (const float*)d_in[8];
  float* out = (float*)d_out;

  unsigned short* wsKA = (unsigned short*)d_ws;
  unsigned short* wsQA = (unsigned short*)((char*)d_ws + KA_BYTES);
  unsigned short* wsVt = (unsigned short*)((char*)d_ws + KA_BYTES + QA_BYTES);
  float* wsPart = (float*)((char*)d_ws + PART_OFF);

  prep<<<1536, 256, 0, stream>>>(k, q, v, px, py, bx, by, wsKA, wsQA, wsVt);

  if (ws_size >= WS_SPLIT) {
    attn_rpb_mfma22<<<1024, NT, 0, stream>>>(pz, bz, wsKA, wsQA, wsVt, out, wsPart, 1);
    attn_rpb_combine<<<6144, 256, 0, stream>>>(wsPart, out);
  } else {
    attn_rpb_mfma22<<<512, NT, 0, stream>>>(pz, bz, wsKA, wsQA, wsVt, out, wsPart, 0);
  }
}

// Round 24
// 38.480 us; speedup vs baseline: 1.0155x; 1.0155x over previous
//
#include <hip/hip_runtime.h>
#include <math.h>

// FusedAttentionWithRPB — FINAL (r18/r22 configuration, measured 38.51us
// twice). Architecture summary:
//  - prep (1024 blocks): builds fragment-major KA tiles (K | x-bias cols |
//    y-bias cols, bias*log2e baked) and fragment-major Vt tiles in d_ws,
//    all writes/reads lane-ordered so main's fragment loads are coalesced.
//  - main (1024 LPT chunk-blocks, barrier-free loop, launch_bounds(256,3)):
//    bias-as-MFMA via one-hot-augmented QK^T (K=128), z-bias via 256-entry
//    LDS table, exp2-domain online softmax with defer-max + lazy lsum,
//    P roundtrip through wave-private swizzled LDS, V fragments in regs.
//  - combine (6144 blocks): merges 2-3 flash-decoding partials per row.
// Plateau: latency-bound at 12 waves/CU; no pipe >50%; 17 probes around
// this config were neutral/negative (only barrier-removal helped).

constexpr int Bc = 4, Hc = 8, Sc = 1024, Dc = 64;
constexpr int NT = 256;
constexpr float LOG2E = 1.44269504f;

constexpr size_t KA_BYTES   = (size_t)32 * 16 * 16384;            // 8 MB (frag-major)
constexpr size_t VT_BYTES   = (size_t)32 * 16 * 8192;             // 4 MB
constexpr size_t PART_OFF   = KA_BYTES + VT_BYTES;
constexpr size_t PART_BYTES = (size_t)32 * 12 * 3 * 64 * 66 * sizeof(float);
constexpr size_t WS_SPLIT   = PART_OFF + PART_BYTES;

typedef __attribute__((ext_vector_type(8))) short bf16x8;
typedef __attribute__((ext_vector_type(4))) float f32x4;

// chunk tables: cid -> (qi, ktb, kte, part), heavy-first (LPT)  [validated]
__device__ __constant__ signed char CQI[32] =
  {15,11,11,10,15,15,14,14,14,13,13,12,10, 9, 9, 8,13,12,12, 8, 7, 7, 6, 3, 6, 5, 5, 4, 2, 4, 1, 0};
__device__ __constant__ signed char CKTB[32] =
  {10, 0, 6, 5, 0, 5, 0, 5,10, 4, 9, 8, 0, 0, 5, 4, 0, 0, 4, 0, 0, 4, 3, 0, 0, 0, 3, 2, 0, 0, 0, 0};
__device__ __constant__ signed char CKTE[32] =
  {16, 6,12,11, 5,10, 5,10,15, 9,14,13, 5, 5,10, 9, 4, 4, 8, 4, 4, 8, 7, 4, 3, 3, 6, 5, 3, 2, 2, 1};
__device__ __constant__ signed char CPT[32] =
  { 2, 0, 1, 1, 0, 1, 0, 1, 2, 1, 2, 2, 0, 0, 1, 1, 0, 0, 1, 0, 0, 1, 1, 0, 0, 0, 1, 1, 0, 0, 0, 0};

__device__ __forceinline__ unsigned short f2bf(float f) {
  union { float f; unsigned u; } x; x.f = f;
  unsigned r = x.u + 0x7FFFu + ((x.u >> 16) & 1u);
  return (unsigned short)(r >> 16);
}
__device__ __forceinline__ bf16x8 pack8(float4 a, float4 b) {
  bf16x8 r;
  r[0] = (short)f2bf(a.x); r[1] = (short)f2bf(a.y);
  r[2] = (short)f2bf(a.z); r[3] = (short)f2bf(a.w);
  r[4] = (short)f2bf(b.x); r[5] = (short)f2bf(b.y);
  r[6] = (short)f2bf(b.z); r[7] = (short)f2bf(b.w);
  return r;
}
__device__ __forceinline__ float4 sc4(float4 a, float s) {
  return make_float4(a.x*s, a.y*s, a.z*s, a.w*s);
}
__device__ __forceinline__ float ex2(float x) {
  return __builtin_amdgcn_exp2f(x);
}
// swizzled byte offset inside a 64x64 bf16 tile (128B rows) for Ps
__device__ __forceinline__ int swzb(int row, int col) {
  return ((row << 7) + (col << 1)) ^ ((row & 7) << 4);
}
template<int C>
__device__ __forceinline__ float dppf(float x) {
  return __int_as_float(__builtin_amdgcn_update_dpp(
      __float_as_int(x), __float_as_int(x), C, 0xF, 0xF, false));
}
__device__ __forceinline__ float red_max16(float x) {
  x = fmaxf(x, dppf<0xB1>(x));  x = fmaxf(x, dppf<0x4E>(x));
  x = fmaxf(x, dppf<0x141>(x)); x = fmaxf(x, dppf<0x140>(x));
  return x;
}
__device__ __forceinline__ float red_sum16(float x) {
  x += dppf<0xB1>(x);  x += dppf<0x4E>(x);
  x += dppf<0x141>(x); x += dppf<0x140>(x);
  return x;
}

// ---- fused pre-pass.
// Blocks 0-511 (bh,kt): KA tile FRAGMENT-MAJOR, 16 frags x 1KB. Frag f
// (ct=f>>2, ks=f&3), lane l=16lg+lr holds 16B = KA_logical[key=16ct+lr]
// [slot=4ks+lg]; logical slots: 0-7 = K dims, 8-11 = x-bias, 12-15 = y-bias
// (bias pre-scaled by log2e; Q carries 0.125*log2e).
// Blocks 512-1023: Vt fragment-major (validated r14).
__global__ __launch_bounds__(256) void prep(
    const float* __restrict__ kg, const float* __restrict__ vg,
    const int* __restrict__ px, const int* __restrict__ py,
    const float* __restrict__ bx, const float* __restrict__ by,
    unsigned short* __restrict__ wsKA, unsigned short* __restrict__ wsVt)
{
  __shared__ float tile[64 * 68];
  __shared__ float bxh[61], byh[61];
  __shared__ int kxs[64], kys[64];
  const int t = threadIdx.x;
  if (blockIdx.x < 512) {
    const int bh = blockIdx.x >> 4, kt = blockIdx.x & 15;
    const int b = bh >> 3, h = bh & 7;
    // coalesced stage of the 64x64 f32 K tile
    const int row = t >> 2, c4 = t & 3;
    const float4* src = (const float4*)(kg + ((size_t)bh * Sc + kt*64 + row) * Dc + c4*16);
    #pragma unroll
    for (int jj = 0; jj < 4; ++jj)
      *(float4*)&tile[row * 68 + c4*16 + 4*jj] = src[jj];
    if (t < 61)                   bxh[t]      = bx[t * Hc + h] * LOG2E;
    else if (t >= 64 && t < 125)  byh[t - 64] = by[(t - 64) * Hc + h] * LOG2E;
    if (t < 64) { kxs[t] = px[b*Sc + kt*64 + t]; kys[t] = py[b*Sc + kt*64 + t]; }
    __syncthreads();
    const int l = t & 63, fg = t >> 6;
    const int lg = l >> 4, lr = l & 15;
    unsigned short* tbase = wsKA + (size_t)(bh * 16 + kt) * 8192;
    #pragma unroll
    for (int ff = 0; ff < 4; ++ff) {
      const int f = ff * 4 + fg;
      const int ct = f >> 2, ks = f & 3;
      const int keyl = 16*ct + lr, slot = 4*ks + lg;
      bf16x8 out;
      if (slot < 8) {
        float4 a = *(const float4*)&tile[keyl * 68 + slot*8];
        float4 bb = *(const float4*)&tile[keyl * 68 + slot*8 + 4];
        out = pack8(a, bb);
      } else if (slot < 12) {
        const int p = slot - 8, kx = kxs[keyl];
        #pragma unroll
        for (int j = 0; j < 8; ++j) {
          int ix = 8*p + j - kx; ix = ix < -30 ? -30 : (ix > 30 ? 30 : ix);
          out[j] = (short)f2bf(bxh[ix + 30]);
        }
      } else {
        const int p = slot - 12, ky = kys[keyl];
        #pragma unroll
        for (int j = 0; j < 8; ++j) {
          int iy = 8*p + j - ky; iy = iy < -30 ? -30 : (iy > 30 ? 30 : iy);
          out[j] = (short)f2bf(byh[iy + 30]);
        }
      }
      *(bf16x8*)(tbase + f * 512 + l * 8) = out;
    }
  } else {
    const int bid = blockIdx.x - 512;
    const int bh = bid >> 4, tt = bid & 15;
    const int row = t >> 2, c4 = t & 3;
    const float4* src = (const float4*)(vg + ((size_t)bh * Sc + tt*64 + row) * Dc + c4*16);
    #pragma unroll
    for (int jj = 0; jj < 4; ++jj)
      *(float4*)&tile[row * 68 + c4*16 + 4*jj] = src[jj];
    __syncthreads();
    const int d = t & 63, cg = t >> 6;
    const int nt_ = d >> 4, lr = d & 15;
    unsigned short* tbase = wsVt + (size_t)(bh * 16 + tt) * 4096;
    #pragma unroll
    for (int cc = 0; cc < 2; ++cc) {
      const int c = 2*cg + cc;            // keys [8c, 8c+8)
      const int ks = c >> 2, lg = c & 3;
      bf16x8 vv;
      #pragma unroll
      for (int jj = 0; jj < 8; ++jj)
        vv[jj] = (short)f2bf(tile[(8*c + jj) * 68 + d]);
      *(bf16x8*)(tbase + (nt_*2 + ks) * 512 + (16*lg + lr) * 8) = vv;
    }
  }
}

// ---- main kernel: NO per-step barrier; all operands from L1/L2-hot ws
__global__ __launch_bounds__(NT, 3) void attn_rpb_final(
    const float* __restrict__ qg,
    const int* __restrict__ px, const int* __restrict__ py, const int* __restrict__ pz,
    const float* __restrict__ bz,
    const unsigned short* __restrict__ wsKA, const unsigned short* __restrict__ wsVt,
    float* __restrict__ outg, float* __restrict__ wsPart, int mode)
{
  int qi, ktb, kte, part, np, bh;
  {
    const int j = blockIdx.x;
    if (mode == 0) {
      const int idx = j & 255; bh = idx >> 3; const int r3 = idx & 7;
      qi = (j < 256) ? (15 - r3) : r3;
      ktb = 0; kte = qi + 1; part = 0; np = 1;
    } else {
      bh = j & 31;
      const int cid = j >> 5;
      qi = CQI[cid]; ktb = CKTB[cid]; kte = CKTE[cid]; part = CPT[cid];
      np = (qi < 4) ? 1 : ((qi < 12) ? 2 : 3);
    }
  }
  const int h = bh & 7, b = bh >> 3;

  __shared__ unsigned short Ps[64 * 64];   // 8 KB, wave-private rows
  __shared__ float BZ2[256];

  const int t  = threadIdx.x;
  const int w  = t >> 6;
  const int l  = t & 63;
  const int lg = l >> 4;
  const int lr = l & 15;
  const size_t bhOff = (size_t)bh * Sc;
  const int q0 = qi * 64;

  const char* kaSrc = (const char*)wsKA;
  const char* vtSrc = (const char*)wsVt;

  // ---- prologue: BZ2; Q/one-hot frags -> regs
  {
    int dzz = (t >> 4) - (t & 15); dzz = dzz < -10 ? -10 : (dzz > 10 ? 10 : dzz);
    BZ2[t] = bz[(dzz + 10) * Hc + h] * LOG2E;
  }
  const int myrow = q0 + 16*w + lr;
  bf16x8 aq[4];
  {
    const float* qrow = qg + (bhOff + myrow) * Dc;
    #pragma unroll
    for (int ks = 0; ks < 2; ++ks) {
      float4 f0 = *(const float4*)(qrow + 32*ks + 8*lg);
      float4 f1 = *(const float4*)(qrow + 32*ks + 8*lg + 4);
      aq[ks] = pack8(sc4(f0, 0.125f * LOG2E), sc4(f1, 0.125f * LOG2E));
    }
    const int qxr = px[b*Sc + myrow], qyr = py[b*Sc + myrow];
    const short one = (short)0x3F80;
    #pragma unroll
    for (int m = 0; m < 8; ++m) {
      aq[2][m] = (qxr == 8*lg + m) ? one : (short)0;
      aq[3][m] = (qyr == 8*lg + m) ? one : (short)0;
    }
  }
  int rowg[4], qz16[4];
  #pragma unroll
  for (int r = 0; r < 4; ++r) {
    const int rl = 16*w + 4*lg + r;
    rowg[r] = q0 + rl;
    qz16[r] = pz[b*Sc + q0 + rl] << 4;
  }

  float mrow[4], lsumP[4];
  f32x4 O[4];
  const f32x4 zero4 = {0.f, 0.f, 0.f, 0.f};
  #pragma unroll
  for (int r = 0; r < 4; ++r) { mrow[r] = -INFINITY; lsumP[r] = 0.f; }
  #pragma unroll
  for (int nt_ = 0; nt_ < 4; ++nt_) O[nt_] = zero4;

  __syncthreads();   // BZ2 visible (ONLY barrier in the kernel)

  for (int kt = ktb; kt < kte; ++kt) {
    const int k0 = kt * 64;
    const char* kaTile = kaSrc + (size_t)(bh*16 + kt) * 16384 + l*16;
    const char* vtile  = vtSrc + (size_t)(bh*16 + kt) * 8192 + l*16;

    // ---- V frags + kz -> regs (coalesced, L1/L2-hot)
    bf16x8 vv[8];
    #pragma unroll
    for (int f = 0; f < 8; ++f)
      vv[f] = *(const bf16x8*)(vtile + f*1024);
    int kzv[4];
    #pragma unroll
    for (int ct = 0; ct < 4; ++ct) kzv[ct] = pz[b*Sc + k0 + 16*ct + lr];

    // ---- S = [Q|onehot] x KA^T  (K=128, 16 MFMA; frags coalesced)
    f32x4 s[4];
    #pragma unroll
    for (int ct = 0; ct < 4; ++ct) {
      s[ct] = zero4;
      #pragma unroll
      for (int ks = 0; ks < 4; ++ks) {
        bf16x8 bk = *(const bf16x8*)(kaTile + (ct*4 + ks) * 1024);
        s[ct] = __builtin_amdgcn_mfma_f32_16x16x32_bf16(aq[ks], bk, s[ct], 0, 0, 0);
      }
    }

    // ---- z-bias + causal mask
    const bool diag = (kt == qi);
    #pragma unroll
    for (int ct = 0; ct < 4; ++ct) {
      const int colg = k0 + 16*ct + lr;
      #pragma unroll
      for (int r = 0; r < 4; ++r) {
        float val = s[ct][r] + BZ2[qz16[r] | kzv[ct]];
        if (diag && colg > rowg[r]) val = -INFINITY;
        s[ct][r] = val;
      }
    }

    // ---- online softmax: defer-max (log2 domain) + lazy lsum
    float tmax[4];
    #pragma unroll
    for (int r = 0; r < 4; ++r) {
      tmax[r] = fmaxf(fmaxf(s[0][r], s[1][r]), fmaxf(s[2][r], s[3][r]));
      tmax[r] = red_max16(tmax[r]);
    }
    float dmax = fmaxf(fmaxf(tmax[0] - mrow[0], tmax[1] - mrow[1]),
                       fmaxf(tmax[2] - mrow[2], tmax[3] - mrow[3]));
    if (__any(dmax > 11.5f)) {
      #pragma unroll
      for (int r = 0; r < 4; ++r) {
        const float mn = fmaxf(mrow[r], tmax[r]);
        const float alpha = ex2(mrow[r] - mn);
        mrow[r] = mn;
        lsumP[r] *= alpha;
        #pragma unroll
        for (int nt_ = 0; nt_ < 4; ++nt_) O[nt_][r] *= alpha;
      }
    }
    #pragma unroll
    for (int ct = 0; ct < 4; ++ct) {
      #pragma unroll
      for (int r = 0; r < 4; ++r)
        s[ct][r] = ex2(s[ct][r] - mrow[r]);
    }
    #pragma unroll
    for (int r = 0; r < 4; ++r)
      lsumP[r] += (s[0][r] + s[1][r]) + (s[2][r] + s[3][r]);

    // ---- P -> bf16 -> Ps (wave-private rows; in-wave ordering suffices)
    #pragma unroll
    for (int ct = 0; ct < 4; ++ct) {
      #pragma unroll
      for (int r = 0; r < 4; ++r)
        *(unsigned short*)((char*)Ps + swzb(16*w + 4*lg + r, 16*ct + lr)) = f2bf(s[ct][r]);
    }
    bf16x8 pa[2];
    pa[0] = *(const bf16x8*)((const char*)Ps + swzb(16*w + lr, 8*lg));
    pa[1] = *(const bf16x8*)((const char*)Ps + swzb(16*w + lr, 8*lg + 32));

    // ---- O += P V
    #pragma unroll
    for (int nt_ = 0; nt_ < 4; ++nt_) {
      #pragma unroll
      for (int ks = 0; ks < 2; ++ks)
        O[nt_] = __builtin_amdgcn_mfma_f32_16x16x32_bf16(pa[ks], vv[nt_*2 + ks], O[nt_], 0, 0, 0);
    }
    // no barrier: next iteration's loads are independent (pure reads)
  }

  // ---- epilogue: reduce lsum across the 16 lanes once
  float lsum[4];
  #pragma unroll
  for (int r = 0; r < 4; ++r) lsum[r] = red_sum16(lsumP[r]);

  if (np == 1) {
    #pragma unroll
    for (int r = 0; r < 4; ++r) {
      const float inv = 1.0f / lsum[r];
      #pragma unroll
      for (int nt_ = 0; nt_ < 4; ++nt_)
        outg[(bhOff + q0 + 16*w + 4*lg + r) * Dc + 16*nt_ + lr] = O[nt_][r] * inv;
    }
  } else {
    float* base = wsPart + ((((size_t)bh * 12 + (qi - 4)) * 3 + part) * 64) * 66;
    #pragma unroll
    for (int r = 0; r < 4; ++r) {
      float* rowp = base + (16*w + 4*lg + r) * 66;
      #pragma unroll
      for (int nt_ = 0; nt_ < 4; ++nt_)
        rowp[16*nt_ + lr] = O[nt_][r];
      if (lr == 0) { rowp[64] = mrow[r]; rowp[65] = lsum[r]; }
    }
  }
}

// merge 2-3 partials per (bh, qi>=4) row; m in LOG2 domain -> exp2 weights
__global__ __launch_bounds__(256) void attn_rpb_combine(
    const float* __restrict__ wsPart, float* __restrict__ outg)
{
  const int t = threadIdx.x;
  const int ridx = blockIdx.x * 4 + (t >> 6);
  const int d = t & 63;
  const int bh = ridx / 768;
  const int rem = ridx - bh * 768;
  const int qj = rem >> 6;
  const int rl = rem & 63;
  const float* p0 = wsPart + (((size_t)bh * 12 + qj) * 3 + 0) * 64 * 66 + (size_t)rl * 66;
  const float* p1 = p0 + 64 * 66;
  const float m0 = p0[64], l0 = p0[65];
  const float m1 = p1[64], l1 = p1[65];
  float m = fmaxf(m0, m1);
  float o, lc;
  if (qj >= 8) {
    const float* p2 = p1 + 64 * 66;
    const float m2 = p2[64], l2 = p2[65];
    m = fmaxf(m, m2);
    const float w0 = __builtin_amdgcn_exp2f(m0 - m);
    const float w1 = __builtin_amdgcn_exp2f(m1 - m);
    const float w2 = __builtin_amdgcn_exp2f(m2 - m);
    lc = l0 * w0 + l1 * w1 + l2 * w2;
    o  = p0[d] * w0 + p1[d] * w1 + p2[d] * w2;
  } else {
    const float w0 = __builtin_amdgcn_exp2f(m0 - m);
    const float w1 = __builtin_amdgcn_exp2f(m1 - m);
    lc = l0 * w0 + l1 * w1;
    o  = p0[d] * w0 + p1[d] * w1;
  }
  outg[((size_t)bh * Sc + (qj + 4) * 64 + rl) * Dc + d] = o / lc;
}

extern "C" void kernel_launch(void* const* d_in, const int* in_sizes, int n_in,
                              void* d_out, int out_size, void* d_ws, size_t ws_size,
                              hipStream_t stream) {
  const float* q  = (const float*)d_in[0];
  const float* k  = (const float*)d_in[1];
  const float* v  = (const float*)d_in[2];
  const int*   px = (const int*)d_in[3];
  const int*   py = (const int*)d_in[4];
  const int*   pz = (const int*)d_in[5];
  const float* bx = (const float*)d_in[6];
  const float* by = (const float*)d_in[7];
  const float* bz = (const float*)d_in[8];
  float* out = (float*)d_out;

  unsigned short* wsKA = (unsigned short*)d_ws;
  unsigned short* wsVt = (unsigned short*)((char*)d_ws + KA_BYTES);
  float* wsPart = (float*)((char*)d_ws + PART_OFF);

  prep<<<1024, 256, 0, stream>>>(k, v, px, py, bx, by, wsKA, wsVt);

  if (ws_size >= WS_SPLIT) {
    attn_rpb_final<<<1024, NT, 0, stream>>>(q, px, py, pz, bz, wsKA, wsVt, out, wsPart, 1);
    attn_rpb_combine<<<6144, 256, 0, stream>>>(wsPart, out);
  } else {
    attn_rpb_final<<<512, NT, 0, stream>>>(q, px, py, pz, bz, wsKA, wsVt, out, wsPart, 0);
  }
}